// Round 1
// baseline (1429.870 us; speedup 1.0000x reference)
//
#include <hip/hip_runtime.h>
#include <stdint.h>

// Problem constants (from reference): B=2, S=2048, V=32000, E=H=512, L=3
#define BB 2
#define SS 2048
#define VV 32000
#define HH 512
#define LL 3
#define ROWS (BB * SS)      // 4096
#define G3 (3 * HH)         // 1536

#define NCHUNK 64
#define CLEN (SS / NCHUNK)  // 32

typedef __attribute__((ext_vector_type(8))) __bf16 bf16x8;
typedef __attribute__((ext_vector_type(4))) float f32x4;

// float -> bf16 round-to-nearest-even (bit trick, avoids header dependency)
__device__ __forceinline__ unsigned short f2bf(float f) {
    union { float f; unsigned int u; } cv; cv.f = f;
    unsigned int u = cv.u;
    u += 0x7fffu + ((u >> 16) & 1u);
    return (unsigned short)(u >> 16);
}

// ---------------- embedding gather: x[row] = emb[ids[row]] ----------------
__global__ __launch_bounds__(256) void embed_k(const int* __restrict__ ids,
                                               const float* __restrict__ emb,
                                               float* __restrict__ x) {
    int idx = blockIdx.x * blockDim.x + threadIdx.x;   // over ROWS * (HH/4)
    int row = idx >> 7;            // HH/4 = 128 float4 per row
    int c4  = idx & 127;
    int id = ids[row];
    *(float4*)(x + (size_t)row * HH + c4 * 4) =
        *(const float4*)(emb + (size_t)id * HH + c4 * 4);
}

// ---------------- fp32 -> bf16 bulk convert ----------------
__global__ __launch_bounds__(256) void tobf16_k(const float* __restrict__ in,
                                                unsigned short* __restrict__ outp,
                                                int n4) {
    int i = blockIdx.x * blockDim.x + threadIdx.x;
    if (i >= n4) return;
    float4 v = *(const float4*)(in + (size_t)i * 4);
    unsigned short o[4] = { f2bf(v.x), f2bf(v.y), f2bf(v.z), f2bf(v.w) };
    *(uint2*)(outp + (size_t)i * 4) = *(uint2*)o;
}

// ---------------- LayerNorm over H=512, one wave per row, writes bf16 ------
__global__ __launch_bounds__(256) void ln_k(const float* __restrict__ x,
                                            const float* __restrict__ w,
                                            const float* __restrict__ b,
                                            unsigned short* __restrict__ xn) {
    int wid  = (blockIdx.x * blockDim.x + threadIdx.x) >> 6;  // global wave = row
    int lane = threadIdx.x & 63;
    if (wid >= ROWS) return;
    const float* xr = x + (size_t)wid * HH;
    float4 v0 = *(const float4*)(xr + lane * 8);
    float4 v1 = *(const float4*)(xr + lane * 8 + 4);
    float vs[8] = { v0.x, v0.y, v0.z, v0.w, v1.x, v1.y, v1.z, v1.w };
    float s = 0.f, q = 0.f;
#pragma unroll
    for (int j = 0; j < 8; j++) { s += vs[j]; q += vs[j] * vs[j]; }
#pragma unroll
    for (int off = 32; off; off >>= 1) {
        s += __shfl_xor(s, off);
        q += __shfl_xor(q, off);
    }
    float mean = s * (1.f / HH);
    float var  = q * (1.f / HH) - mean * mean;
    float r    = rsqrtf(var + 1e-5f);
    unsigned short o[8];
#pragma unroll
    for (int j = 0; j < 8; j++) {
        float wj = w[lane * 8 + j];
        float bj = b ? b[lane * 8 + j] : 0.f;
        o[j] = f2bf((vs[j] - mean) * r * wj + bj);
    }
    *(uint4*)(xn + (size_t)wid * HH + lane * 8) = *(uint4*)o;
}

// ---------------- bf16 MFMA GEMM: C(MxN) = A(MxK) * Bt(NxK)^T + bias -------
// 128x128 tile, BK=32, 256 threads (4 waves, each 64x64 via 4x4 mfma 16x16x32).
// LDS rows padded 32->40 elements: conflict-free b128 reads/writes.
#define BM 128
#define BN 128
#define BK 32
#define PADK 40

__global__ __launch_bounds__(256) void gemm_bt(const unsigned short* __restrict__ A,
                                               const unsigned short* __restrict__ Bt,
                                               const float* __restrict__ bias,
                                               float* __restrict__ C,
                                               int K, int ldc) {
    __shared__ __align__(16) unsigned short lA[BM * PADK];
    __shared__ __align__(16) unsigned short lB[BN * PADK];
    int m0 = blockIdx.x * BM;
    int n0 = blockIdx.y * BN;
    int t = threadIdx.x;
    int lane = t & 63;
    int w = t >> 6;
    int wm = (w >> 1) * 64, wn = (w & 1) * 64;

    f32x4 acc[4][4];
#pragma unroll
    for (int i = 0; i < 4; i++)
#pragma unroll
        for (int j = 0; j < 4; j++) acc[i][j] = (f32x4){0.f, 0.f, 0.f, 0.f};

    int fm = lane & 15;
    int fq = (lane >> 4) * 8;
    int nkt = K / BK;
    for (int kt = 0; kt < nkt; kt++) {
        int k0 = kt * BK;
        uint4 ra[2], rb[2];
#pragma unroll
        for (int r2 = 0; r2 < 2; r2++) {
            int idx = r2 * 256 + t;                 // 0..511
            int row = idx >> 2, ce = (idx & 3) * 8; // element offset in row
            ra[r2] = *(const uint4*)(A  + (size_t)(m0 + row) * K + k0 + ce);
            rb[r2] = *(const uint4*)(Bt + (size_t)(n0 + row) * K + k0 + ce);
        }
        __syncthreads();   // previous iter's fragment reads complete
#pragma unroll
        for (int r2 = 0; r2 < 2; r2++) {
            int idx = r2 * 256 + t;
            int row = idx >> 2, ce = (idx & 3) * 8;
            *(uint4*)(lA + row * PADK + ce) = ra[r2];
            *(uint4*)(lB + row * PADK + ce) = rb[r2];
        }
        __syncthreads();
        bf16x8 af[4], bfr[4];
#pragma unroll
        for (int i = 0; i < 4; i++)
            af[i] = *(const bf16x8*)(lA + (wm + i * 16 + fm) * PADK + fq);
#pragma unroll
        for (int j = 0; j < 4; j++)
            bfr[j] = *(const bf16x8*)(lB + (wn + j * 16 + fm) * PADK + fq);
#pragma unroll
        for (int i = 0; i < 4; i++)
#pragma unroll
            for (int j = 0; j < 4; j++)
                acc[i][j] = __builtin_amdgcn_mfma_f32_16x16x32_bf16(
                    af[i], bfr[j], acc[i][j], 0, 0, 0);
    }
    // epilogue: C/D layout col = lane&15, row = (lane>>4)*4 + reg
    int cl = lane & 15, q4 = (lane >> 4) * 4;
#pragma unroll
    for (int i = 0; i < 4; i++) {
#pragma unroll
        for (int j = 0; j < 4; j++) {
            int col = n0 + wn + j * 16 + cl;
            float bv = bias ? bias[col] : 0.f;
#pragma unroll
            for (int r = 0; r < 4; r++) {
                int row = m0 + wm + i * 16 + q4 + r;
                C[(size_t)row * ldc + col] = acc[i][j][r] + bv;
            }
        }
    }
}

// ---------------- scan phase 1: gate math + per-chunk affine summary -------
// thread tid: ch = tid&1023 (= b*H+h), c = tid>>10 (chunk). Rewrites gates
// in place: slot0 <- f' (forget), slot1 <- v = i'*g(tilde).
__global__ __launch_bounds__(256) void scan1_k(float* __restrict__ gates,
                                               float* __restrict__ Ach,
                                               float* __restrict__ Bch) {
    int tid = blockIdx.x * blockDim.x + threadIdx.x;
    int ch = tid & (BB * HH - 1);
    int c  = tid >> 10;
    int b = ch >> 9, h = ch & (HH - 1);
    float a = 1.f, acc = 0.f;
    size_t base = ((size_t)b * SS + (size_t)c * CLEN) * G3 + h;
    for (int s = 0; s < CLEN; s++) {
        float fg = gates[base];
        float ig = gates[base + HH];
        float tg = gates[base + 2 * HH];
        float sf = 1.f / (1.f + expf(-fg));
        float si = 1.f / (1.f + expf(-ig));
        float inv = 1.f / (sf + si);
        float fp = sf * inv;                       // f' = sig(f)/(sig(f)+sig(i))
        float ip = si * inv;
        float g  = tg >= 0.f ? tg + 0.5f : 1.f / (1.f + expf(-tg));
        float v  = ip * g;
        gates[base] = fp;
        gates[base + HH] = v;
        a = fp * a;
        acc = fp * acc + v;                        // compose h -> fp*h + v
        base += G3;
    }
    Ach[tid] = a;
    Bch[tid] = acc;
}

// ---------------- scan phase 2: scan across chunk summaries ---------------
__global__ __launch_bounds__(256) void scan2_k(const float* __restrict__ Ach,
                                               const float* __restrict__ Bch,
                                               float* __restrict__ hin) {
    int ch = blockIdx.x * blockDim.x + threadIdx.x;  // 1024 channels
    float hh = 0.5f;                                  // h0 = g(0) = 0.5
    for (int c = 0; c < NCHUNK; c++) {
        int i = c * (BB * HH) + ch;
        hin[i] = hh;                                  // h entering chunk c
        hh = Ach[i] * hh + Bch[i];
    }
}

// ---------------- scan phase 3: replay chunk, x += h (residual fused) ------
__global__ __launch_bounds__(256) void scan3_k(const float* __restrict__ gates,
                                               const float* __restrict__ hin,
                                               float* __restrict__ x) {
    int tid = blockIdx.x * blockDim.x + threadIdx.x;
    int ch = tid & (BB * HH - 1);
    int c  = tid >> 10;
    int b = ch >> 9, h = ch & (HH - 1);
    float hh = hin[c * (BB * HH) + ch];
    size_t gbase = ((size_t)b * SS + (size_t)c * CLEN) * G3 + h;
    size_t xbase = ((size_t)b * SS + (size_t)c * CLEN) * HH + h;
    for (int s = 0; s < CLEN; s++) {
        float fp = gates[gbase];
        float v  = gates[gbase + HH];
        hh = fp * hh + v;
        x[xbase] += hh;                               // x = inp + h
        gbase += G3;
        xbase += HH;
    }
}

extern "C" void kernel_launch(void* const* d_in, const int* in_sizes, int n_in,
                              void* d_out, int out_size, void* d_ws, size_t ws_size,
                              hipStream_t stream) {
    const int*   ids  = (const int*)  d_in[0];
    const float* emb  = (const float*)d_in[1];
    const float* Ws   = (const float*)d_in[2];
    const float* bs   = (const float*)d_in[3];
    const float* lnw  = (const float*)d_in[4];
    const float* lnb  = (const float*)d_in[5];
    const float* flnw = (const float*)d_in[6];
    const float* fcw  = (const float*)d_in[7];
    const float* fcb  = (const float*)d_in[8];
    float* out = (float*)d_out;

    // workspace layout (~76 MB total)
    char* p = (char*)d_ws;
    float* x            = (float*)p;           p += (size_t)ROWS * HH * 4;        // 8 MB
    unsigned short* xnb = (unsigned short*)p;  p += (size_t)ROWS * HH * 2;        // 4 MB
    unsigned short* wsb = (unsigned short*)p;  p += (size_t)LL * G3 * HH * 2;     // 4.7 MB
    unsigned short* fwb = (unsigned short*)p;  p += (size_t)VV * HH * 2;          // 32.8 MB
    float* gates        = (float*)p;           p += (size_t)ROWS * G3 * 4;        // 25 MB
    float* Ach          = (float*)p;           p += (size_t)NCHUNK * BB * HH * 4; // 256 KB
    float* Bch          = (float*)p;           p += (size_t)NCHUNK * BB * HH * 4;
    float* hin          = (float*)p;           p += (size_t)NCHUNK * BB * HH * 4;

    embed_k<<<ROWS * (HH / 4) / 256, 256, 0, stream>>>(ids, emb, x);
    tobf16_k<<<(LL * G3 * HH / 4 + 255) / 256, 256, 0, stream>>>(Ws, wsb, LL * G3 * HH / 4);
    tobf16_k<<<(VV * HH / 4 + 255) / 256, 256, 0, stream>>>(fcw, fwb, VV * HH / 4);

    for (int l = 0; l < LL; l++) {
        ln_k<<<ROWS / 4, 256, 0, stream>>>(x, lnw + l * HH, lnb + l * HH, xnb);
        gemm_bt<<<dim3(ROWS / BM, G3 / BN), 256, 0, stream>>>(
            xnb, wsb + (size_t)l * G3 * HH, bs + l * G3, gates, HH, G3);
        scan1_k<<<NCHUNK * BB * HH / 256, 256, 0, stream>>>(gates, Ach, Bch);
        scan2_k<<<BB * HH / 256, 256, 0, stream>>>(Ach, Bch, hin);
        scan3_k<<<NCHUNK * BB * HH / 256, 256, 0, stream>>>(gates, hin, x);
    }

    ln_k<<<ROWS / 4, 256, 0, stream>>>(x, flnw, nullptr, xnb);
    gemm_bt<<<dim3(ROWS / BM, VV / BN), 256, 0, stream>>>(xnb, fwb, fcb, out, HH, VV);
}